// Round 11
// baseline (252.212 us; speedup 1.0000x reference)
//
#include <hip/hip_runtime.h>
#include <hip/hip_fp16.h>

#define N_NODES 100000
#define N_EDGES 1600000
#define N_GRAPHS 256
#define NB 1563              // ceil(100000 / 64) buckets of 64 nodes
#define SBLOCKS 128          // hist/scatter blocks; 12500 edges each
#define GB1 782              // gemm tiles (ceil(100000/128))

typedef _Float16 half8 __attribute__((ext_vector_type(8)));
typedef float f32x4 __attribute__((ext_vector_type(4)));

__device__ __forceinline__ unsigned pack2(float a, float b) {
    __half2 h = __floats2half2_rn(a, b);
    return *reinterpret_cast<unsigned*>(&h);
}

// ---------------- W prep: Wt16[n][k] = fp16(W[k][n]), both weights ----------
__global__ __launch_bounds__(256) void wprep_kernel(const float* __restrict__ W1,
                                                    const float* __restrict__ W2,
                                                    __half* __restrict__ Wt1,
                                                    __half* __restrict__ Wt2) {
    int b = blockIdx.x;
    const float* W = (b < 64) ? W1 : W2;
    __half* Wt = (b < 64) ? Wt1 : Wt2;
    int t = (b & 63) * 256 + threadIdx.x;   // 0..16383
    int n = t >> 7, k = t & 127;
    Wt[t] = (__half)W[k * 128 + n];
}

// ---------------- fused LDS-free MFMA-GEMM / edge-histogram -----------------
// histBlocks!=0: grid 1024; (bid&7)==0 -> hist id=bid>>3 (128 blocks), else
// gemm id=(bid>>3)*7+(bid&7)-1 (guard id<GB1). hist: LDS histogram of dst>>6
// -> cnt2d row (no global atomics). gemm: NO LDS, NO barrier — per-wave MFMA
// fragments loaded straight from global. A: lanes (lr,lg) cover 16 rows x 4
// k-octets = whole 64B lines, each X element read exactly once. B: all
// blocks reread the same 32KB Wt (L1/L2-hot). Layouts HW-verified (guide s3).
__global__ __launch_bounds__(256) void gemmhist_kernel(const float* __restrict__ Xf,
                                                       const __half* __restrict__ Xh,
                                                       const __half* __restrict__ Wt,
                                                       const float* __restrict__ dinv,
                                                       __half* __restrict__ HT,
                                                       int xf16, int withDinv,
                                                       const int* __restrict__ dst,
                                                       int* __restrict__ cnt2d,
                                                       int histBlocks) {
    __shared__ int lcnt[NB];                 // 6.3 KB; hist blocks only
    const int tid = threadIdx.x;
    int bid = blockIdx.x;
    bool isHist = false;
    int id = bid;
    if (histBlocks) {
        if ((bid & 7) == 0) { isHist = true; id = bid >> 3; }
        else {
            id = (bid >> 3) * 7 + (bid & 7) - 1;
            if (id >= GB1) return;
        }
    }

    if (isHist) {
        for (int i = tid; i < NB; i += 256) lcnt[i] = 0;
        __syncthreads();
        const int per = (N_EDGES + SBLOCKS - 1) / SBLOCKS;   // 12500
        int e0 = id * per, e1 = min(e0 + per, N_EDGES);
        for (int e = e0 + tid; e < e1; e += 256)
            atomicAdd(&lcnt[dst[e] >> 6], 1);
        __syncthreads();
        for (int i = tid; i < NB; i += 256)
            cnt2d[id * NB + i] = lcnt[i];
        return;
    }

    const int row0 = id * 128;
    const int wv = tid >> 6;
    const int lane = tid & 63;
    const int lr = lane & 15;
    const int lg = lane >> 4;
    const int r0 = min(row0 + wv * 32 + lr, N_NODES - 1);
    const int r1 = min(row0 + wv * 32 + 16 + lr, N_NODES - 1);

    f32x4 acc[2][8];
#pragma unroll
    for (int mt = 0; mt < 2; ++mt)
#pragma unroll
        for (int nt = 0; nt < 8; ++nt) acc[mt][nt] = (f32x4){0.f, 0.f, 0.f, 0.f};

#pragma unroll
    for (int ks = 0; ks < 4; ++ks) {
        const int kb = ks * 32 + lg * 8;
        half8 a0, a1;
        if (xf16) {
            a0 = *reinterpret_cast<const half8*>(&Xh[(size_t)r0 * 128 + kb]);
            a1 = *reinterpret_cast<const half8*>(&Xh[(size_t)r1 * 128 + kb]);
        } else {
            float4 v0 = *(const float4*)&Xf[(size_t)r0 * 128 + kb];
            float4 v1 = *(const float4*)&Xf[(size_t)r0 * 128 + kb + 4];
            float4 u0 = *(const float4*)&Xf[(size_t)r1 * 128 + kb];
            float4 u1 = *(const float4*)&Xf[(size_t)r1 * 128 + kb + 4];
            a0[0] = (_Float16)v0.x; a0[1] = (_Float16)v0.y;
            a0[2] = (_Float16)v0.z; a0[3] = (_Float16)v0.w;
            a0[4] = (_Float16)v1.x; a0[5] = (_Float16)v1.y;
            a0[6] = (_Float16)v1.z; a0[7] = (_Float16)v1.w;
            a1[0] = (_Float16)u0.x; a1[1] = (_Float16)u0.y;
            a1[2] = (_Float16)u0.z; a1[3] = (_Float16)u0.w;
            a1[4] = (_Float16)u1.x; a1[5] = (_Float16)u1.y;
            a1[6] = (_Float16)u1.z; a1[7] = (_Float16)u1.w;
        }
        half8 b[8];
#pragma unroll
        for (int nt = 0; nt < 8; ++nt)
            b[nt] = *reinterpret_cast<const half8*>(&Wt[(size_t)(nt * 16 + lr) * 128 + kb]);
#pragma unroll
        for (int nt = 0; nt < 8; ++nt) {
            acc[0][nt] = __builtin_amdgcn_mfma_f32_16x16x32_f16(a0, b[nt], acc[0][nt], 0, 0, 0);
            acc[1][nt] = __builtin_amdgcn_mfma_f32_16x16x32_f16(a1, b[nt], acc[1][nt], 0, 0, 0);
        }
    }

#pragma unroll
    for (int mt = 0; mt < 2; ++mt) {
#pragma unroll
        for (int i = 0; i < 4; ++i) {
            int rr = row0 + wv * 32 + mt * 16 + lg * 4 + i;
            if (rr < N_NODES) {
                float di = withDinv ? dinv[rr] : 1.0f;
#pragma unroll
                for (int nt = 0; nt < 8; ++nt)
                    HT[(size_t)rr * 128 + nt * 16 + lr] = (__half)(acc[mt][nt][i] * di);
            }
        }
    }
}

// ---------------- scan2d: 2 buckets/block, 128-wide segmented scan ----------
__global__ __launch_bounds__(256) void scan2d_kernel(int* __restrict__ cnt2d,
                                                     int* __restrict__ bucket_cnt) {
    __shared__ int ts[256];
    int t = threadIdx.x;
    int j = t & 127;          // hist-block index
    int bucket = blockIdx.x * 2 + (t >> 7);
    int v = (bucket < NB) ? cnt2d[j * NB + bucket] : 0;
    ts[t] = v;
    __syncthreads();
    for (int off = 1; off < 128; off <<= 1) {
        int y = (j >= off) ? ts[t - off] : 0;
        __syncthreads();
        ts[t] += y;
        __syncthreads();
    }
    if (bucket < NB) {
        cnt2d[j * NB + bucket] = ts[t] - v;   // exclusive
        if (j == 127) bucket_cnt[bucket] = ts[t];
    }
}

// ---------------- scanB: exclusive scan over bucket totals ------------------
#define BVPT 7   // 256*7 = 1792 >= NB
__global__ __launch_bounds__(256) void scanB_kernel(const int* __restrict__ bucket_cnt,
                                                    int* __restrict__ bucket_off) {
    __shared__ int tsum[256];
    int tid = threadIdx.x;
    int v[BVPT];
    int s = 0;
#pragma unroll
    for (int j = 0; j < BVPT; ++j) {
        int idx = tid * BVPT + j;
        v[j] = (idx < NB) ? bucket_cnt[idx] : 0;
        s += v[j];
    }
    tsum[tid] = s;
    __syncthreads();
    for (int off = 1; off < 256; off <<= 1) {
        int y = (tid >= off) ? tsum[tid - off] : 0;
        __syncthreads();
        tsum[tid] += y;
        __syncthreads();
    }
    int run = (tid > 0) ? tsum[tid - 1] : 0;
#pragma unroll
    for (int j = 0; j < BVPT; ++j) {
        int idx = tid * BVPT + j;
        if (idx < NB) bucket_off[idx] = run;
        run += v[j];
    }
    if (tid == 255) bucket_off[NB] = tsum[255];
}

// ---------------- scatter: exact-packed bucket scatter (LDS cursors) --------
__global__ __launch_bounds__(1024) void scatter_kernel(const int* __restrict__ src,
                                                       const int* __restrict__ dst,
                                                       const int* __restrict__ cnt2d,
                                                       const int* __restrict__ bucket_off,
                                                       unsigned* __restrict__ pairbuf) {
    __shared__ int lcur[NB];
    const int tid = threadIdx.x;
    const int blk = blockIdx.x;
    for (int i = tid; i < NB; i += 1024)
        lcur[i] = bucket_off[i] + cnt2d[blk * NB + i];
    __syncthreads();
    const int per = (N_EDGES + SBLOCKS - 1) / SBLOCKS;
    int e0 = blk * per, e1 = min(e0 + per, N_EDGES);
    for (int e = e0 + tid; e < e1; e += 1024) {
        int d = dst[e];
        int b = d >> 6;
        int p = atomicAdd(&lcur[b], 1);
        pairbuf[p] = ((unsigned)(d & 63) << 17) | (unsigned)src[e];
    }
}

// ---------------- per-bucket counting sort (wave-0 shfl scan) ---------------
__global__ __launch_bounds__(256) void localsort_kernel(const unsigned* __restrict__ pairbuf,
                                                        const int* __restrict__ bucket_off,
                                                        int* __restrict__ csr_src,
                                                        int* __restrict__ row_off,
                                                        float* __restrict__ dinv) {
    __shared__ int ldeg[64];
    __shared__ int lcur[64];
    int tid = threadIdx.x;
    int b = blockIdx.x;
    int base = bucket_off[b];
    int cnt = bucket_off[b + 1] - base;
    const unsigned* pb = pairbuf + base;
    int n0 = b << 6;

    if (tid < 64) ldeg[tid] = 0;
    __syncthreads();
    for (int i = tid; i < cnt; i += 256)
        atomicAdd(&ldeg[pb[i] >> 17], 1);
    __syncthreads();
    if (tid < 64) {                       // wave 0: shfl inclusive scan, no barriers
        int d = ldeg[tid];
        int x = d;
#pragma unroll
        for (int off = 1; off < 64; off <<= 1) {
            int y = __shfl_up(x, off);
            if (tid >= off) x += y;
        }
        int ex = x - d;                   // exclusive prefix
        lcur[tid] = ex;
        int n = n0 + tid;
        if (n < N_NODES) {
            row_off[n] = base + ex;
            dinv[n] = rsqrtf((float)d + 1.0f);
        }
    }
    __syncthreads();
    for (int i = tid; i < cnt; i += 256) {
        unsigned w = pb[i];
        int dl = w >> 17;
        int s = (int)(w & 0x1FFFFu);
        int p = atomicAdd(&lcur[dl], 1);
        csr_src[base + p] = s;
    }
}

// ---------------- gather (template DV) --------------------------------------
__device__ __forceinline__ void add8(float* a, uint4 w) {
    float2 p0 = __half22float2(*reinterpret_cast<__half2*>(&w.x));
    float2 p1 = __half22float2(*reinterpret_cast<__half2*>(&w.y));
    float2 p2 = __half22float2(*reinterpret_cast<__half2*>(&w.z));
    float2 p3 = __half22float2(*reinterpret_cast<__half2*>(&w.w));
    a[0] += p0.x; a[1] += p0.y; a[2] += p1.x; a[3] += p1.y;
    a[4] += p2.x; a[5] += p2.y; a[6] += p3.x; a[7] += p3.y;
}
__device__ __forceinline__ void fma8(float* a, uint4 w, float s) {
    float2 p0 = __half22float2(*reinterpret_cast<__half2*>(&w.x));
    float2 p1 = __half22float2(*reinterpret_cast<__half2*>(&w.y));
    float2 p2 = __half22float2(*reinterpret_cast<__half2*>(&w.z));
    float2 p3 = __half22float2(*reinterpret_cast<__half2*>(&w.w));
    a[0] = fmaf(s, p0.x, a[0]); a[1] = fmaf(s, p0.y, a[1]);
    a[2] = fmaf(s, p1.x, a[2]); a[3] = fmaf(s, p1.y, a[3]);
    a[4] = fmaf(s, p2.x, a[4]); a[5] = fmaf(s, p2.y, a[5]);
    a[6] = fmaf(s, p3.x, a[6]); a[7] = fmaf(s, p3.y, a[7]);
}
template<bool DV>
__global__ __launch_bounds__(256) void gather_kernel(const int* __restrict__ row_off,
                                                     const int* __restrict__ csr_src,
                                                     const __half* __restrict__ ht,
                                                     const float* __restrict__ dinv,
                                                     const float* __restrict__ bias,
                                                     __half* __restrict__ Y) {
    int t = blockIdx.x * 256 + threadIdx.x;
    int n = t >> 4;
    if (n >= N_NODES) return;
    int f = (t & 15) * 8;
    int e0 = row_off[n];
    int e1 = (n < N_NODES - 1) ? row_off[n + 1] : N_EDGES;
    const __half* htf = ht + f;
    float dn = dinv[n];

    float a0[8] = {0,0,0,0,0,0,0,0};
    float a1[8] = {0,0,0,0,0,0,0,0};
    float a2[8] = {0,0,0,0,0,0,0,0};
    float a3[8] = {0,0,0,0,0,0,0,0};
    {   // self-loop term
        uint4 w = *(const uint4*)&htf[(size_t)n * 128];
        if (DV) fma8(a0, w, dn); else add8(a0, w);
    }
    int e = e0;
    for (; e + 4 <= e1; e += 4) {
        int s0 = csr_src[e], s1 = csr_src[e + 1];
        int s2 = csr_src[e + 2], s3 = csr_src[e + 3];
        uint4 w0 = *(const uint4*)&htf[(size_t)s0 * 128];
        uint4 w1 = *(const uint4*)&htf[(size_t)s1 * 128];
        uint4 w2 = *(const uint4*)&htf[(size_t)s2 * 128];
        uint4 w3 = *(const uint4*)&htf[(size_t)s3 * 128];
        if (DV) {
            fma8(a0, w0, dinv[s0]); fma8(a1, w1, dinv[s1]);
            fma8(a2, w2, dinv[s2]); fma8(a3, w3, dinv[s3]);
        } else {
            add8(a0, w0); add8(a1, w1); add8(a2, w2); add8(a3, w3);
        }
    }
    for (; e < e1; ++e) {
        int s = csr_src[e];
        uint4 w = *(const uint4*)&htf[(size_t)s * 128];
        if (DV) fma8(a0, w, dinv[s]); else add8(a0, w);
    }

    float4 bb0 = *(const float4*)&bias[f];
    float4 bb1 = *(const float4*)&bias[f + 4];
    float r0 = fmaxf((a0[0]+a1[0]+a2[0]+a3[0]) * dn + bb0.x, 0.0f);
    float r1 = fmaxf((a0[1]+a1[1]+a2[1]+a3[1]) * dn + bb0.y, 0.0f);
    float r2 = fmaxf((a0[2]+a1[2]+a2[2]+a3[2]) * dn + bb0.z, 0.0f);
    float r3 = fmaxf((a0[3]+a1[3]+a2[3]+a3[3]) * dn + bb0.w, 0.0f);
    float r4 = fmaxf((a0[4]+a1[4]+a2[4]+a3[4]) * dn + bb1.x, 0.0f);
    float r5 = fmaxf((a0[5]+a1[5]+a2[5]+a3[5]) * dn + bb1.y, 0.0f);
    float r6 = fmaxf((a0[6]+a1[6]+a2[6]+a3[6]) * dn + bb1.z, 0.0f);
    float r7 = fmaxf((a0[7]+a1[7]+a2[7]+a3[7]) * dn + bb1.w, 0.0f);
    uint4 o;
    o.x = pack2(r0, r1);
    o.y = pack2(r2, r3);
    o.z = pack2(r4, r5);
    o.w = pack2(r6, r7);
    *(uint4*)&Y[(size_t)n * 128 + f] = o;
}

// ---------------- fused mean-pool + head: one block per graph ---------------
__global__ __launch_bounds__(256) void poolout_kernel(const __half* __restrict__ Y,
                                                      const int* __restrict__ batch,
                                                      const float* __restrict__ w_out,
                                                      const float* __restrict__ b_out,
                                                      float* __restrict__ out) {
    __shared__ float red[8][128];
    __shared__ float pr[128];
    int g = blockIdx.x;
    int tid = threadIdx.x;
    int lo = 0, hi = N_NODES;
    while (lo < hi) { int m = (lo + hi) >> 1; if (batch[m] < g) lo = m + 1; else hi = m; }
    int lo2 = lo, hi2 = N_NODES;
    while (lo2 < hi2) { int m = (lo2 + hi2) >> 1; if (batch[m] < g + 1) lo2 = m + 1; else hi2 = m; }
    int cnt = lo2 - lo;

    int rslot = tid >> 5;
    int f = (tid & 31) * 4;
    float4 acc = make_float4(0, 0, 0, 0);
    for (int n = lo + rslot; n < lo2; n += 8) {
        uint2 w = *(const uint2*)&Y[(size_t)n * 128 + f];
        float2 p0 = __half22float2(*reinterpret_cast<__half2*>(&w.x));
        float2 p1 = __half22float2(*reinterpret_cast<__half2*>(&w.y));
        acc.x += p0.x; acc.y += p0.y; acc.z += p1.x; acc.w += p1.y;
    }
    *(float4*)&red[rslot][f] = acc;
    __syncthreads();
    if (tid < 128) {
        float s = 0.0f;
#pragma unroll
        for (int r = 0; r < 8; ++r) s += red[r][tid];
        pr[tid] = s * w_out[tid];
    }
    __syncthreads();
    for (int off = 64; off >= 1; off >>= 1) {
        if (tid < off) pr[tid] += pr[tid + off];
        __syncthreads();
    }
    if (tid == 0)
        out[g] = pr[0] / fmaxf((float)cnt, 1.0f) + b_out[0];
}

extern "C" void kernel_launch(void* const* d_in, const int* in_sizes, int n_in,
                              void* d_out, int out_size, void* d_ws, size_t ws_size,
                              hipStream_t stream) {
    const float* x     = (const float*)d_in[0];
    const int*   edge  = (const int*)d_in[1];   // [2, E]
    const int*   batch = (const int*)d_in[2];
    const float* w1    = (const float*)d_in[3];
    const float* b1    = (const float*)d_in[4];
    const float* w2    = (const float*)d_in[5];
    const float* b2    = (const float*)d_in[6];
    const float* w_out = (const float*)d_in[7];
    const float* b_out = (const float*)d_in[8];
    float* out = (float*)d_out;

    char* ws = (char*)d_ws;
    size_t off = 0;
    auto alloc = [&](size_t bytes) {
        void* p = ws + off;
        off += (bytes + 511) & ~(size_t)511;
        return p;
    };
    const size_t FEAT_BYTES = (size_t)N_NODES * 128 * 4;     // 51.2 MB
    __half*   ht16       = (__half*)alloc(FEAT_BYTES / 2);   // 25.6 MB
    __half*   y16        = (__half*)alloc(FEAT_BYTES / 2);   // 25.6 MB (aliases pairbuf)
    unsigned* pairbuf    = (unsigned*)y16;                   // 6.4 MB, dead after localsort
    float*    dinv       = (float*)alloc(N_NODES * 4);
    int*      row_off    = (int*)alloc(N_NODES * 4);
    int*      csr_src    = (int*)alloc(N_EDGES * 4);         // 6.4 MB
    int*      cnt2d      = (int*)alloc((size_t)SBLOCKS * NB * 4);  // 0.8 MB
    int*      bucket_cnt = (int*)alloc((NB + 1) * 4);
    int*      bucket_off = (int*)alloc((NB + 1) * 4);
    __half*   wt1        = (__half*)alloc(128 * 128 * 2);
    __half*   wt2        = (__half*)alloc(128 * 128 * 2);

    const int* src = edge;
    const int* dst = edge + N_EDGES;

    // ----- weight prep (both, one launch) -----
    wprep_kernel<<<128, 256, 0, stream>>>(w1, w2, wt1, wt2);

    // ----- K1: layer-1 GEMM (raw XW, dinv deferred) fused with edge hist ----
    gemmhist_kernel<<<1024, 256, 0, stream>>>(
        x, (const __half*)nullptr, wt1, (const float*)nullptr, ht16,
        0, 0, dst, cnt2d, 1);

    // ----- CSR build -----
    scan2d_kernel<<<(NB + 1) / 2, 256, 0, stream>>>(cnt2d, bucket_cnt);
    scanB_kernel<<<1, 256, 0, stream>>>(bucket_cnt, bucket_off);
    scatter_kernel<<<SBLOCKS, 1024, 0, stream>>>(src, dst, cnt2d, bucket_off, pairbuf);
    localsort_kernel<<<NB, 256, 0, stream>>>(pairbuf, bucket_off, csr_src, row_off, dinv);

    // ----- layer 1 gather (applies dinv[s] per edge) -----
    gather_kernel<true><<<(N_NODES * 16 + 255) / 256, 256, 0, stream>>>(
        row_off, csr_src, ht16, dinv, b1, y16);

    // ----- layer 2 -----
    gemmhist_kernel<<<GB1, 256, 0, stream>>>(
        (const float*)nullptr, y16, wt2, dinv, ht16, 1, 1,
        (const int*)nullptr, (int*)nullptr, 0);
    gather_kernel<false><<<(N_NODES * 16 + 255) / 256, 256, 0, stream>>>(
        row_off, csr_src, ht16, dinv, b2, y16);

    // ----- fused pool + head -----
    poolout_kernel<<<N_GRAPHS, 256, 0, stream>>>(y16, batch, w_out, b_out, out);
}

// Round 12
// 232.989 us; speedup vs baseline: 1.0825x; 1.0825x over previous
//
#include <hip/hip_runtime.h>
#include <hip/hip_fp16.h>

#define N_NODES 100000
#define N_EDGES 1600000
#define N_GRAPHS 256
#define NB 1563              // ceil(100000 / 64) buckets of 64 nodes
#define SBLOCKS 256          // hist/scatter blocks; 6250 edges each
#define GB1 782              // gemm tiles (ceil(100000/128))

typedef _Float16 half8 __attribute__((ext_vector_type(8)));
typedef float f32x4 __attribute__((ext_vector_type(4)));

__device__ __forceinline__ unsigned pack2(float a, float b) {
    __half2 h = __floats2half2_rn(a, b);
    return *reinterpret_cast<unsigned*>(&h);
}

// ---------------- W prep: Wt16[n][k] = fp16(W[k][n]), both weights ----------
__global__ __launch_bounds__(256) void wprep_kernel(const float* __restrict__ W1,
                                                    const float* __restrict__ W2,
                                                    __half* __restrict__ Wt1,
                                                    __half* __restrict__ Wt2) {
    int b = blockIdx.x;
    const float* W = (b < 64) ? W1 : W2;
    __half* Wt = (b < 64) ? Wt1 : Wt2;
    int t = (b & 63) * 256 + threadIdx.x;   // 0..16383
    int n = t >> 7, k = t & 127;
    Wt[t] = (__half)W[k * 128 + n];
}

// ---------------- fused MFMA-GEMM / edge-histogram kernel (R10 structure) ---
__global__ __launch_bounds__(256) void gemmhist_kernel(const float* __restrict__ Xf,
                                                       const __half* __restrict__ Xh,
                                                       const __half* __restrict__ Wt,
                                                       const float* __restrict__ dinv,
                                                       __half* __restrict__ HT,
                                                       int xf16, int withDinv,
                                                       const int* __restrict__ dst,
                                                       int* __restrict__ cnt2d,
                                                       int histBlocks) {
    __shared__ __align__(16) char smem[69632];
    const int tid = threadIdx.x;
    int bid = blockIdx.x;
    bool isHist = false;
    int id = bid;
    if (histBlocks) {
        if (bid < 1024) {
            if ((bid & 3) == 0) { isHist = true; id = bid >> 2; }
            else id = (bid >> 2) * 3 + (bid & 3) - 1;
        } else {
            id = 768 + (bid - 1024);
        }
    }

    if (isHist) {
        int* lcnt = (int*)smem;
        for (int i = tid; i < NB; i += 256) lcnt[i] = 0;
        __syncthreads();
        const int per = (N_EDGES + SBLOCKS - 1) / SBLOCKS;   // 6250
        int e0 = id * per, e1 = min(e0 + per, N_EDGES);
        for (int e = e0 + tid; e < e1; e += 256)
            atomicAdd(&lcnt[dst[e] >> 6], 1);
        __syncthreads();
        for (int i = tid; i < NB; i += 256)
            cnt2d[id * NB + i] = lcnt[i];                    // coalesced row
        return;
    }

    typedef __half (*TileT)[136];
    TileT Xl = (TileT)smem;                  // 128 x 136 halves
    TileT Wl = (TileT)(smem + 34816);        // 128 x 136 halves
    const int row0 = id * 128;

#pragma unroll
    for (int i = 0; i < 8; ++i) {
        int idx = tid + i * 256;             // 0..2047
        int n = idx >> 4, c0 = (idx & 15) * 8;
        *(uint4*)&Wl[n][c0] = *(const uint4*)&Wt[n * 128 + c0];
    }
    if (xf16) {
#pragma unroll
        for (int i = 0; i < 8; ++i) {
            int idx = tid + i * 256;
            int r = idx >> 4, c0 = (idx & 15) * 8;
            int rr = min(row0 + r, N_NODES - 1);
            *(uint4*)&Xl[r][c0] = *(const uint4*)&Xh[(size_t)rr * 128 + c0];
        }
    } else {
#pragma unroll
        for (int i = 0; i < 16; ++i) {
            int idx = tid + i * 256;         // 0..4095
            int r = idx >> 5, c0 = (idx & 31) * 4;
            int rr = min(row0 + r, N_NODES - 1);
            float4 v = *(const float4*)&Xf[(size_t)rr * 128 + c0];
            uint2 o;
            o.x = pack2(v.x, v.y);
            o.y = pack2(v.z, v.w);
            *(uint2*)&Xl[r][c0] = o;
        }
    }
    __syncthreads();

    const int wv = tid >> 6;
    const int lane = tid & 63;
    const int lr = lane & 15;
    const int lg = lane >> 4;

    f32x4 acc[2][8];
#pragma unroll
    for (int mt = 0; mt < 2; ++mt)
#pragma unroll
        for (int nt = 0; nt < 8; ++nt) acc[mt][nt] = (f32x4){0.f, 0.f, 0.f, 0.f};

#pragma unroll
    for (int ks = 0; ks < 4; ++ks) {
        const int kb = ks * 32 + lg * 8;
        half8 a0 = *reinterpret_cast<const half8*>(&Xl[wv * 32 + lr][kb]);
        half8 a1 = *reinterpret_cast<const half8*>(&Xl[wv * 32 + 16 + lr][kb]);
        half8 b[8];
#pragma unroll
        for (int nt = 0; nt < 8; ++nt)
            b[nt] = *reinterpret_cast<const half8*>(&Wl[nt * 16 + lr][kb]);
#pragma unroll
        for (int nt = 0; nt < 8; ++nt) {
            acc[0][nt] = __builtin_amdgcn_mfma_f32_16x16x32_f16(a0, b[nt], acc[0][nt], 0, 0, 0);
            acc[1][nt] = __builtin_amdgcn_mfma_f32_16x16x32_f16(a1, b[nt], acc[1][nt], 0, 0, 0);
        }
    }

#pragma unroll
    for (int mt = 0; mt < 2; ++mt) {
#pragma unroll
        for (int i = 0; i < 4; ++i) {
            int rr = row0 + wv * 32 + mt * 16 + lg * 4 + i;
            if (rr < N_NODES) {
                float di = withDinv ? dinv[rr] : 1.0f;
#pragma unroll
                for (int nt = 0; nt < 8; ++nt)
                    HT[(size_t)rr * 128 + nt * 16 + lr] = (__half)(acc[mt][nt][i] * di);
            }
        }
    }
}

// ---------------- scan2d: exclusive scan of cnt2d along block dim (R10) -----
__global__ __launch_bounds__(256) void scan2d_kernel(int* __restrict__ cnt2d,
                                                     int* __restrict__ bucket_cnt) {
    __shared__ int ts[256];
    int i = blockIdx.x;       // bucket
    int t = threadIdx.x;      // hist-block index
    int v = cnt2d[t * NB + i];
    ts[t] = v;
    __syncthreads();
    for (int off = 1; off < 256; off <<= 1) {
        int y = (t >= off) ? ts[t - off] : 0;
        __syncthreads();
        ts[t] += y;
        __syncthreads();
    }
    cnt2d[t * NB + i] = ts[t] - v;   // exclusive
    if (t == 255) bucket_cnt[i] = ts[255];
}

// ---------------- scatter (+ fused bucket scan): LDS cursors ----------------
// Each block redundantly computes the exclusive scan over bucket_cnt (1563
// values, BVPT-scan, ~2K cycles) -> lcur[i] = boff[i] + cnt2d[blk][i].
// Block 0 also writes bucket_off for localsort. Deletes the scanB dispatch.
#define BVPT 7   // 256*7 = 1792 >= NB
__global__ __launch_bounds__(256) void scatter_kernel(const int* __restrict__ src,
                                                      const int* __restrict__ dst,
                                                      const int* __restrict__ cnt2d,
                                                      const int* __restrict__ bucket_cnt,
                                                      int* __restrict__ bucket_off,
                                                      unsigned* __restrict__ pairbuf) {
    __shared__ int lcur[NB];
    __shared__ int tsum[256];
    const int tid = threadIdx.x;
    const int blk = blockIdx.x;

    int v[BVPT];
    int s = 0;
#pragma unroll
    for (int j = 0; j < BVPT; ++j) {
        int idx = tid * BVPT + j;
        v[j] = (idx < NB) ? bucket_cnt[idx] : 0;
        s += v[j];
    }
    tsum[tid] = s;
    __syncthreads();
    for (int off = 1; off < 256; off <<= 1) {
        int y = (tid >= off) ? tsum[tid - off] : 0;
        __syncthreads();
        tsum[tid] += y;
        __syncthreads();
    }
    int run = (tid > 0) ? tsum[tid - 1] : 0;
#pragma unroll
    for (int j = 0; j < BVPT; ++j) {
        int idx = tid * BVPT + j;
        if (idx < NB) {
            lcur[idx] = run + cnt2d[blk * NB + idx];
            if (blk == 0) bucket_off[idx] = run;
        }
        run += v[j];
    }
    if (blk == 0 && tid == 255) bucket_off[NB] = tsum[255];
    __syncthreads();

    const int per = (N_EDGES + SBLOCKS - 1) / SBLOCKS;
    int e0 = blk * per, e1 = min(e0 + per, N_EDGES);
    for (int e = e0 + tid; e < e1; e += 256) {
        int d = dst[e];
        int b = d >> 6;
        int p = atomicAdd(&lcur[b], 1);
        pairbuf[p] = ((unsigned)(d & 63) << 17) | (unsigned)src[e];
    }
}

// ---------------- per-bucket counting sort (wave-0 shfl scan) ---------------
__global__ __launch_bounds__(256) void localsort_kernel(const unsigned* __restrict__ pairbuf,
                                                        const int* __restrict__ bucket_off,
                                                        int* __restrict__ csr_src,
                                                        int* __restrict__ row_off,
                                                        float* __restrict__ dinv) {
    __shared__ int ldeg[64];
    __shared__ int lcur[64];
    int tid = threadIdx.x;
    int b = blockIdx.x;
    int base = bucket_off[b];
    int cnt = bucket_off[b + 1] - base;
    const unsigned* pb = pairbuf + base;
    int n0 = b << 6;

    if (tid < 64) ldeg[tid] = 0;
    __syncthreads();
    for (int i = tid; i < cnt; i += 256)
        atomicAdd(&ldeg[pb[i] >> 17], 1);
    __syncthreads();
    if (tid < 64) {                       // wave 0: shfl inclusive scan
        int d = ldeg[tid];
        int x = d;
#pragma unroll
        for (int off = 1; off < 64; off <<= 1) {
            int y = __shfl_up(x, off);
            if (tid >= off) x += y;
        }
        int ex = x - d;                   // exclusive prefix
        lcur[tid] = ex;
        int n = n0 + tid;
        if (n < N_NODES) {
            row_off[n] = base + ex;
            dinv[n] = rsqrtf((float)d + 1.0f);
        }
    }
    __syncthreads();
    for (int i = tid; i < cnt; i += 256) {
        unsigned w = pb[i];
        int dl = w >> 17;
        int s = (int)(w & 0x1FFFFu);
        int p = atomicAdd(&lcur[dl], 1);
        csr_src[base + p] = s;
    }
}

// ---------------- gathers: two separate named kernels (no template) ---------
__device__ __forceinline__ void add8(float* a, uint4 w) {
    float2 p0 = __half22float2(*reinterpret_cast<__half2*>(&w.x));
    float2 p1 = __half22float2(*reinterpret_cast<__half2*>(&w.y));
    float2 p2 = __half22float2(*reinterpret_cast<__half2*>(&w.z));
    float2 p3 = __half22float2(*reinterpret_cast<__half2*>(&w.w));
    a[0] += p0.x; a[1] += p0.y; a[2] += p1.x; a[3] += p1.y;
    a[4] += p2.x; a[5] += p2.y; a[6] += p3.x; a[7] += p3.y;
}
__device__ __forceinline__ void fma8(float* a, uint4 w, float s) {
    float2 p0 = __half22float2(*reinterpret_cast<__half2*>(&w.x));
    float2 p1 = __half22float2(*reinterpret_cast<__half2*>(&w.y));
    float2 p2 = __half22float2(*reinterpret_cast<__half2*>(&w.z));
    float2 p3 = __half22float2(*reinterpret_cast<__half2*>(&w.w));
    a[0] = fmaf(s, p0.x, a[0]); a[1] = fmaf(s, p0.y, a[1]);
    a[2] = fmaf(s, p1.x, a[2]); a[3] = fmaf(s, p1.y, a[3]);
    a[4] = fmaf(s, p2.x, a[4]); a[5] = fmaf(s, p2.y, a[5]);
    a[6] = fmaf(s, p3.x, a[6]); a[7] = fmaf(s, p3.y, a[7]);
}

// layer 1: ht = raw XW; accumulate dinv[s]*ht[s] (dinv deferred from gemm1)
__global__ __launch_bounds__(256) void gather1_kernel(const int* __restrict__ row_off,
                                                      const int* __restrict__ csr_src,
                                                      const __half* __restrict__ ht,
                                                      const float* __restrict__ dinv,
                                                      const float* __restrict__ bias,
                                                      __half* __restrict__ Y) {
    int t = blockIdx.x * 256 + threadIdx.x;
    int n = t >> 4;
    if (n >= N_NODES) return;
    int f = (t & 15) * 8;
    int e0 = row_off[n];
    int e1 = (n < N_NODES - 1) ? row_off[n + 1] : N_EDGES;
    const __half* htf = ht + f;
    float dn = dinv[n];

    float a0[8] = {0,0,0,0,0,0,0,0};
    float a1[8] = {0,0,0,0,0,0,0,0};
    float a2[8] = {0,0,0,0,0,0,0,0};
    float a3[8] = {0,0,0,0,0,0,0,0};
    fma8(a0, *(const uint4*)&htf[(size_t)n * 128], dn);   // self-loop

    int e = e0;
    for (; e + 4 <= e1; e += 4) {
        int s0 = csr_src[e], s1 = csr_src[e + 1];
        int s2 = csr_src[e + 2], s3 = csr_src[e + 3];
        uint4 w0 = *(const uint4*)&htf[(size_t)s0 * 128];
        uint4 w1 = *(const uint4*)&htf[(size_t)s1 * 128];
        uint4 w2 = *(const uint4*)&htf[(size_t)s2 * 128];
        uint4 w3 = *(const uint4*)&htf[(size_t)s3 * 128];
        fma8(a0, w0, dinv[s0]); fma8(a1, w1, dinv[s1]);
        fma8(a2, w2, dinv[s2]); fma8(a3, w3, dinv[s3]);
    }
    for (; e < e1; ++e) {
        int s = csr_src[e];
        fma8(a0, *(const uint4*)&htf[(size_t)s * 128], dinv[s]);
    }

    float4 bb0 = *(const float4*)&bias[f];
    float4 bb1 = *(const float4*)&bias[f + 4];
    float r0 = fmaxf((a0[0]+a1[0]+a2[0]+a3[0]) * dn + bb0.x, 0.0f);
    float r1 = fmaxf((a0[1]+a1[1]+a2[1]+a3[1]) * dn + bb0.y, 0.0f);
    float r2 = fmaxf((a0[2]+a1[2]+a2[2]+a3[2]) * dn + bb0.z, 0.0f);
    float r3 = fmaxf((a0[3]+a1[3]+a2[3]+a3[3]) * dn + bb0.w, 0.0f);
    float r4 = fmaxf((a0[4]+a1[4]+a2[4]+a3[4]) * dn + bb1.x, 0.0f);
    float r5 = fmaxf((a0[5]+a1[5]+a2[5]+a3[5]) * dn + bb1.y, 0.0f);
    float r6 = fmaxf((a0[6]+a1[6]+a2[6]+a3[6]) * dn + bb1.z, 0.0f);
    float r7 = fmaxf((a0[7]+a1[7]+a2[7]+a3[7]) * dn + bb1.w, 0.0f);
    uint4 o;
    o.x = pack2(r0, r1);
    o.y = pack2(r2, r3);
    o.z = pack2(r4, r5);
    o.w = pack2(r6, r7);
    *(uint4*)&Y[(size_t)n * 128 + f] = o;
}

// layer 2: ht has dinv[row] folded (gemm2 withDinv=1); plain adds
__global__ __launch_bounds__(256) void gather2_kernel(const int* __restrict__ row_off,
                                                      const int* __restrict__ csr_src,
                                                      const __half* __restrict__ ht,
                                                      const float* __restrict__ dinv,
                                                      const float* __restrict__ bias,
                                                      __half* __restrict__ Y) {
    int t = blockIdx.x * 256 + threadIdx.x;
    int n = t >> 4;
    if (n >= N_NODES) return;
    int f = (t & 15) * 8;
    int e0 = row_off[n];
    int e1 = (n < N_NODES - 1) ? row_off[n + 1] : N_EDGES;
    const __half* htf = ht + f;
    float dn = dinv[n];

    float a0[8] = {0,0,0,0,0,0,0,0};
    float a1[8] = {0,0,0,0,0,0,0,0};
    float a2[8] = {0,0,0,0,0,0,0,0};
    float a3[8] = {0,0,0,0,0,0,0,0};
    add8(a0, *(const uint4*)&htf[(size_t)n * 128]);   // self-loop

    int e = e0;
    for (; e + 4 <= e1; e += 4) {
        int s0 = csr_src[e], s1 = csr_src[e + 1];
        int s2 = csr_src[e + 2], s3 = csr_src[e + 3];
        uint4 w0 = *(const uint4*)&htf[(size_t)s0 * 128];
        uint4 w1 = *(const uint4*)&htf[(size_t)s1 * 128];
        uint4 w2 = *(const uint4*)&htf[(size_t)s2 * 128];
        uint4 w3 = *(const uint4*)&htf[(size_t)s3 * 128];
        add8(a0, w0); add8(a1, w1); add8(a2, w2); add8(a3, w3);
    }
    for (; e < e1; ++e)
        add8(a0, *(const uint4*)&htf[(size_t)csr_src[e] * 128]);

    float4 bb0 = *(const float4*)&bias[f];
    float4 bb1 = *(const float4*)&bias[f + 4];
    float r0 = fmaxf((a0[0]+a1[0]+a2[0]+a3[0]) * dn + bb0.x, 0.0f);
    float r1 = fmaxf((a0[1]+a1[1]+a2[1]+a3[1]) * dn + bb0.y, 0.0f);
    float r2 = fmaxf((a0[2]+a1[2]+a2[2]+a3[2]) * dn + bb0.z, 0.0f);
    float r3 = fmaxf((a0[3]+a1[3]+a2[3]+a3[3]) * dn + bb0.w, 0.0f);
    float r4 = fmaxf((a0[4]+a1[4]+a2[4]+a3[4]) * dn + bb1.x, 0.0f);
    float r5 = fmaxf((a0[5]+a1[5]+a2[5]+a3[5]) * dn + bb1.y, 0.0f);
    float r6 = fmaxf((a0[6]+a1[6]+a2[6]+a3[6]) * dn + bb1.z, 0.0f);
    float r7 = fmaxf((a0[7]+a1[7]+a2[7]+a3[7]) * dn + bb1.w, 0.0f);
    uint4 o;
    o.x = pack2(r0, r1);
    o.y = pack2(r2, r3);
    o.z = pack2(r4, r5);
    o.w = pack2(r6, r7);
    *(uint4*)&Y[(size_t)n * 128 + f] = o;
}

// ---------------- fused mean-pool + head: one block per graph ---------------
__global__ __launch_bounds__(256) void poolout_kernel(const __half* __restrict__ Y,
                                                      const int* __restrict__ batch,
                                                      const float* __restrict__ w_out,
                                                      const float* __restrict__ b_out,
                                                      float* __restrict__ out) {
    __shared__ float red[8][128];
    __shared__ float pr[128];
    int g = blockIdx.x;
    int tid = threadIdx.x;
    int lo = 0, hi = N_NODES;
    while (lo < hi) { int m = (lo + hi) >> 1; if (batch[m] < g) lo = m + 1; else hi = m; }
    int lo2 = lo, hi2 = N_NODES;
    while (lo2 < hi2) { int m = (lo2 + hi2) >> 1; if (batch[m] < g + 1) lo2 = m + 1; else hi2 = m; }
    int cnt = lo2 - lo;

    int rslot = tid >> 5;
    int f = (tid & 31) * 4;
    float4 acc = make_float4(0, 0, 0, 0);
    for (int n = lo + rslot; n < lo2; n += 8) {
        uint2 w = *(const uint2*)&Y[(size_t)n * 128 + f];
        float2 p0 = __half22float2(*reinterpret_cast<__half2*>(&w.x));
        float2 p1 = __half22float2(*reinterpret_cast<__half2*>(&w.y));
        acc.x += p0.x; acc.y += p0.y; acc.z += p1.x; acc.w += p1.y;
    }
    *(float4*)&red[rslot][f] = acc;
    __syncthreads();
    if (tid < 128) {
        float s = 0.0f;
#pragma unroll
        for (int r = 0; r < 8; ++r) s += red[r][tid];
        pr[tid] = s * w_out[tid];
    }
    __syncthreads();
    for (int off = 64; off >= 1; off >>= 1) {
        if (tid < off) pr[tid] += pr[tid + off];
        __syncthreads();
    }
    if (tid == 0)
        out[g] = pr[0] / fmaxf((float)cnt, 1.0f) + b_out[0];
}

extern "C" void kernel_launch(void* const* d_in, const int* in_sizes, int n_in,
                              void* d_out, int out_size, void* d_ws, size_t ws_size,
                              hipStream_t stream) {
    const float* x     = (const float*)d_in[0];
    const int*   edge  = (const int*)d_in[1];   // [2, E]
    const int*   batch = (const int*)d_in[2];
    const float* w1    = (const float*)d_in[3];
    const float* b1    = (const float*)d_in[4];
    const float* w2    = (const float*)d_in[5];
    const float* b2    = (const float*)d_in[6];
    const float* w_out = (const float*)d_in[7];
    const float* b_out = (const float*)d_in[8];
    float* out = (float*)d_out;

    char* ws = (char*)d_ws;
    size_t off = 0;
    auto alloc = [&](size_t bytes) {
        void* p = ws + off;
        off += (bytes + 511) & ~(size_t)511;
        return p;
    };
    const size_t FEAT_BYTES = (size_t)N_NODES * 128 * 4;     // 51.2 MB
    __half*   ht16       = (__half*)alloc(FEAT_BYTES / 2);   // 25.6 MB
    __half*   y16        = (__half*)alloc(FEAT_BYTES / 2);   // 25.6 MB (aliases pairbuf)
    unsigned* pairbuf    = (unsigned*)y16;                   // 6.4 MB, dead after localsort
    float*    dinv       = (float*)alloc(N_NODES * 4);
    int*      row_off    = (int*)alloc(N_NODES * 4);
    int*      csr_src    = (int*)alloc(N_EDGES * 4);         // 6.4 MB
    int*      cnt2d      = (int*)alloc((size_t)SBLOCKS * NB * 4);  // 1.6 MB
    int*      bucket_cnt = (int*)alloc((NB + 1) * 4);
    int*      bucket_off = (int*)alloc((NB + 1) * 4);
    __half*   wt1        = (__half*)alloc(128 * 128 * 2);
    __half*   wt2        = (__half*)alloc(128 * 128 * 2);

    const int* src = edge;
    const int* dst = edge + N_EDGES;

    // ----- weight prep (both, one launch) -----
    wprep_kernel<<<128, 256, 0, stream>>>(w1, w2, wt1, wt2);

    // ----- K1: layer-1 GEMM (raw XW, dinv deferred) fused with edge hist ----
    gemmhist_kernel<<<1024 + (GB1 - 768), 256, 0, stream>>>(
        x, (const __half*)nullptr, wt1, (const float*)nullptr, ht16,
        0, 0, dst, cnt2d, 1);

    // ----- CSR build: scan2d -> scatter(+scanB) -> localsort ----------------
    scan2d_kernel<<<NB, 256, 0, stream>>>(cnt2d, bucket_cnt);
    scatter_kernel<<<SBLOCKS, 256, 0, stream>>>(src, dst, cnt2d, bucket_cnt,
                                                bucket_off, pairbuf);
    localsort_kernel<<<NB, 256, 0, stream>>>(pairbuf, bucket_off, csr_src, row_off, dinv);

    // ----- layer 1 gather (applies dinv[s] per edge) -----
    gather1_kernel<<<(N_NODES * 16 + 255) / 256, 256, 0, stream>>>(
        row_off, csr_src, ht16, dinv, b1, y16);

    // ----- layer 2 -----
    gemmhist_kernel<<<GB1, 256, 0, stream>>>(
        (const float*)nullptr, y16, wt2, dinv, ht16, 1, 1,
        (const int*)nullptr, (int*)nullptr, 0);
    gather2_kernel<<<(N_NODES * 16 + 255) / 256, 256, 0, stream>>>(
        row_off, csr_src, ht16, dinv, b2, y16);

    // ----- fused pool + head -----
    poolout_kernel<<<N_GRAPHS, 256, 0, stream>>>(y16, batch, w_out, b_out, out);
}